// Round 1
// baseline (43.441 us; speedup 1.0000x reference)
//
#include <hip/hip_runtime.h>

// SparseVoxelConverter: depth -> xyz -> voxel indices, masked.
// B=16, H=W=512, N = B*H*W = 4,194,304.
// Output (concatenated flat, all written as float32):
//   [0,        4N) : indices [N,4]  (b, vx, vy, vz) or -1 if masked
//   [4N,      7N)  : values  [N,3]  rgb (NHWC) or 0 if masked
//   [7N,      8N)  : mask    [N]    1.0 / 0.0

#define SVC_B  16
#define SVC_H  512
#define SVC_W  512
#define SVC_HW (SVC_H * SVC_W)       // 262144 = 2^18
#define SVC_N  (SVC_B * SVC_HW)      // 4,194,304

__global__ __launch_bounds__(256)
void svc_kernel(const float* __restrict__ rgb,
                const float* __restrict__ depth,
                float* __restrict__ out_idx,   // [N*4]
                float* __restrict__ out_val,   // [N*3]
                float* __restrict__ out_mask)  // [N]
{
    const int tid = blockIdx.x * blockDim.x + threadIdx.x;
    const int n0  = tid << 2;                  // first of 4 consecutive points
    if (n0 >= SVC_N) return;

    const int b   = n0 >> 18;                  // / HW
    const int rem = n0 & (SVC_HW - 1);         // within-image offset
    const int v   = rem >> 9;                  // / W
    const int u0  = rem & (SVC_W - 1);         // % W  (4 points share b, v)

    // Coalesced vector loads: depth + 3 rgb channel streams.
    const float4 d4 = *reinterpret_cast<const float4*>(depth + (size_t)b * SVC_HW + rem);
    const float* rgbb = rgb + (size_t)b * 3 * SVC_HW + rem;
    const float4 r4 = *reinterpret_cast<const float4*>(rgbb);
    const float4 g4 = *reinterpret_cast<const float4*>(rgbb + SVC_HW);
    const float4 b4 = *reinterpret_cast<const float4*>(rgbb + 2 * SVC_HW);

    const float dv[4] = {d4.x, d4.y, d4.z, d4.w};
    const float rv[4] = {r4.x, r4.y, r4.z, r4.w};
    const float gv[4] = {g4.x, g4.y, g4.z, g4.w};
    const float bv[4] = {b4.x, b4.y, b4.z, b4.w};

    const float yb = (float)v - 256.0f;        // (v - cy), same for all 4
    const float bf = (float)b;

    float oi[16];  // indices, 4 pts x 4
    float ov[12];  // values,  4 pts x 3
    float om[4];   // mask

    #pragma unroll
    for (int i = 0; i < 4; ++i) {
        const float d = dv[i];
        const bool m = (d > 0.1f) & (d < 10.0f);
        // x = (u - cx) * d / fx ; fx = cx = 256
        const float x = ((float)(u0 + i) - 256.0f) * d * (1.0f / 256.0f);
        const float y = yb * d * (1.0f / 256.0f);
        // norm = (coord + 1) * 32 ; vox = clip(trunc(norm), 0, 63)
        const float vx = fminf(fmaxf(truncf((x + 1.0f) * 32.0f), 0.0f), 63.0f);
        const float vy = fminf(fmaxf(truncf((y + 1.0f) * 32.0f), 0.0f), 63.0f);
        const float vz = fminf(fmaxf(truncf((d + 1.0f) * 32.0f), 0.0f), 63.0f);

        oi[i * 4 + 0] = m ? bf : -1.0f;
        oi[i * 4 + 1] = m ? vx : -1.0f;
        oi[i * 4 + 2] = m ? vy : -1.0f;
        oi[i * 4 + 3] = m ? vz : -1.0f;
        ov[i * 3 + 0] = m ? rv[i] : 0.0f;
        ov[i * 3 + 1] = m ? gv[i] : 0.0f;
        ov[i * 3 + 2] = m ? bv[i] : 0.0f;
        om[i] = m ? 1.0f : 0.0f;
    }

    // Vectorized stores. n0 is a multiple of 4 -> all segments 16B-aligned.
    float4* pi = reinterpret_cast<float4*>(out_idx + (size_t)n0 * 4);   // 64 B
    pi[0] = make_float4(oi[0],  oi[1],  oi[2],  oi[3]);
    pi[1] = make_float4(oi[4],  oi[5],  oi[6],  oi[7]);
    pi[2] = make_float4(oi[8],  oi[9],  oi[10], oi[11]);
    pi[3] = make_float4(oi[12], oi[13], oi[14], oi[15]);

    float4* pv = reinterpret_cast<float4*>(out_val + (size_t)n0 * 3);   // 48 B
    pv[0] = make_float4(ov[0], ov[1], ov[2],  ov[3]);
    pv[1] = make_float4(ov[4], ov[5], ov[6],  ov[7]);
    pv[2] = make_float4(ov[8], ov[9], ov[10], ov[11]);

    *reinterpret_cast<float4*>(out_mask + n0) = make_float4(om[0], om[1], om[2], om[3]);
}

extern "C" void kernel_launch(void* const* d_in, const int* in_sizes, int n_in,
                              void* d_out, int out_size, void* d_ws, size_t ws_size,
                              hipStream_t stream) {
    const float* rgb   = (const float*)d_in[0];
    const float* depth = (const float*)d_in[1];

    float* out_idx  = (float*)d_out;                     // N*4
    float* out_val  = out_idx + (size_t)SVC_N * 4;       // N*3
    float* out_mask = out_val + (size_t)SVC_N * 3;       // N

    const int threads = 256;
    const int groups  = SVC_N / 4;                       // 1,048,576
    const int blocks  = groups / threads;                // 4096
    svc_kernel<<<blocks, threads, 0, stream>>>(rgb, depth, out_idx, out_val, out_mask);
}